// Round 3
// 208.592 us; speedup vs baseline: 1.0163x; 1.0163x over previous
//
#include <hip/hip_runtime.h>

// OuterMean: algebraic collapse.
// out[i,j,d] = L[i,d] + R[j,d], where
//   S[i,d] = mean_m LN(x)[m,i,d]                    (LN over last dim, eps 1e-5)
//   L = (S @ w_left  + b_left ) @ w_out
//   R = (S @ w_right + b_right) @ w_out + b_out
//
// Workspace layout (floats): L[0:65536], R[65536:131072]  (S never hits global)

#define DIM 128
#define NI  512
#define NM  256

// Native vector type for nontemporal builtins (HIP float4 is a struct and is
// rejected by __builtin_nontemporal_*).
typedef float f32x4 __attribute__((ext_vector_type(4)));

// ---------------- Kernel A: fused LN + mean_m + both projection chains ------
// One block per i. 512 threads = 8 waves. Each wave handles TWO m-rows per
// iteration: lanes 0..31 hold row m_a (float4 = 4 d each), lanes 32..63 hold
// row m_b. Row reduction is a 32-lane shuffle tree (offsets 16..1 never cross
// the half boundary). 16 iterations cover all 256 m.
// Then the block immediately runs both 128x128 projection chains on S[i,:]
// held in LDS, writing only L[i,:], R[i,:] (128 floats each) to global.
__global__ __launch_bounds__(512) void ln_mean_project_kernel(
    const float* __restrict__ x,
    const float* __restrict__ ln_g,    const float* __restrict__ ln_b,
    const float* __restrict__ w_left,  const float* __restrict__ b_left,
    const float* __restrict__ w_right, const float* __restrict__ b_right,
    const float* __restrict__ w_out,   const float* __restrict__ b_out,
    float* __restrict__ L, float* __restrict__ R)
{
    const int i    = blockIdx.x;      // 0..511
    const int tid  = threadIdx.x;     // 0..511
    const int lane = tid & 63;
    const int wave = tid >> 6;        // 0..7
    const int l31  = lane & 31;       // d-quad index (4 floats per lane)
    const int half = lane >> 5;       // which m of the wave's pair

    const float4 g4 = ((const float4*)ln_g)[l31];
    const float4 b4 = ((const float4*)ln_b)[l31];

    float4 acc = make_float4(0.f, 0.f, 0.f, 0.f);

    #pragma unroll 4
    for (int t = 0; t < NM/16; ++t) {
        const int m = (t << 4) + (wave << 1) + half;   // bijective over 0..255
        const f32x4 v = __builtin_nontemporal_load(
            (const f32x4*)(x + (((size_t)(m * NI + i)) << 7)) + l31);

        float s  = v.x + v.y + v.z + v.w;
        float s2 = v.x*v.x + v.y*v.y + v.z*v.z + v.w*v.w;
        #pragma unroll
        for (int off = 16; off; off >>= 1) {           // 32-lane row reduce
            s  += __shfl_xor(s,  off);
            s2 += __shfl_xor(s2, off);
        }
        const float mu   = s * (1.f/128.f);
        const float var  = s2 * (1.f/128.f) - mu*mu;
        const float rstd = rsqrtf(var + 1e-5f);

        acc.x += (v.x - mu) * rstd * g4.x + b4.x;
        acc.y += (v.y - mu) * rstd * g4.y + b4.y;
        acc.z += (v.z - mu) * rstd * g4.z + b4.z;
        acc.w += (v.w - mu) * rstd * g4.w + b4.w;
    }

    __shared__ float4 red[512];   // 8 KiB
    __shared__ float  sS[128];
    __shared__ float  sT[256];    // TL in [0:128], TR in [128:256]

    red[tid] = acc;
    __syncthreads();

    // 16 (wave,half) groups each hold partial sums for the same d-quads.
    if (tid < 32) {
        float4 a = make_float4(0.f, 0.f, 0.f, 0.f);
        #pragma unroll
        for (int g = 0; g < 16; ++g) {
            const float4 r = red[(g << 5) + tid];
            a.x += r.x; a.y += r.y; a.z += r.z; a.w += r.w;
        }
        sS[4*tid+0] = a.x * (1.f/(float)NM);
        sS[4*tid+1] = a.y * (1.f/(float)NM);
        sS[4*tid+2] = a.z * (1.f/(float)NM);
        sS[4*tid+3] = a.w * (1.f/(float)NM);
    }
    __syncthreads();

    // Stage 1: T[h] = sum_d S[d] * W[d,h] + bias[h]; W row-major (DIM,HID).
    if (tid < 256) {
        const int  h   = tid & 127;
        const bool isR = tid >= 128;
        const float* W = isR ? w_right : w_left;
        float a = isR ? b_right[h] : b_left[h];
        #pragma unroll 8
        for (int d = 0; d < DIM; ++d)
            a += sS[d] * W[(d << 7) + h];     // sS broadcast; W coalesced
        sT[tid] = a;
    }
    __syncthreads();

    // Stage 2: out[d] = sum_h T[h] * w_out[h,d]  (+ b_out folded into R).
    if (tid < 256) {
        const int  h   = tid & 127;
        const bool isR = tid >= 128;
        const float* T = sT + (isR ? 128 : 0);
        float a = isR ? b_out[h] : 0.f;
        #pragma unroll 8
        for (int hh = 0; hh < DIM; ++hh)
            a += T[hh] * w_out[(hh << 7) + h];
        (isR ? R : L)[((size_t)i << 7) + h] = a;
    }
}

// ---------------- Kernel B: out[i,j,d] = L[i,d] + R[j,d] --------------------
// 2048 blocks (8/CU), 256 threads. Block b owns (i = b>>2, j-quarter = b&3).
// Each thread: d4 = tid&31, j-lane = tid>>5; L4[i,d4] cached in a register for
// all 16 iterations; R read from L2 (each byte once per block); non-temporal
// stores (128 MiB output can't live in L2 — don't evict R/W with it).
// Per block-iteration the 8 j-rows x 32 d4 stores form 4 KiB contiguous.
__global__ __launch_bounds__(256) void expand_kernel(
    const f32x4* __restrict__ L4,
    const f32x4* __restrict__ R4,
    f32x4* __restrict__ out4)
{
    const int b   = blockIdx.x;          // 0..2047
    const int i   = b >> 2;              // 0..511
    const int jq  = (b & 3) << 7;        // j base: 0,128,256,384
    const int tid = threadIdx.x;
    const int d4  = tid & 31;
    const int jl  = tid >> 5;            // 0..7

    const f32x4 a = L4[(i << 5) + d4];   // held in registers for all 16 iters

    const f32x4* rp = R4   + ((size_t)(jq + jl)          << 5) + d4;
    f32x4*       op = out4 + ((size_t)(i * NI + jq + jl) << 5) + d4;

    #pragma unroll 4
    for (int t = 0; t < 16; ++t) {       // j = jq + jl + 8*t
        const f32x4 rv = rp[(size_t)t << 8];    // 8 rows * 32 float4
        const f32x4 o  = a + rv;
        __builtin_nontemporal_store(o, op + ((size_t)t << 8));
    }
}

extern "C" void kernel_launch(void* const* d_in, const int* in_sizes, int n_in,
                              void* d_out, int out_size, void* d_ws, size_t ws_size,
                              hipStream_t stream) {
    const float* x       = (const float*)d_in[0];
    const float* ln_g    = (const float*)d_in[1];
    const float* ln_b    = (const float*)d_in[2];
    const float* w_left  = (const float*)d_in[3];
    const float* b_left  = (const float*)d_in[4];
    const float* w_right = (const float*)d_in[5];
    const float* b_right = (const float*)d_in[6];
    const float* w_out   = (const float*)d_in[7];
    const float* b_out   = (const float*)d_in[8];

    float* L = (float*)d_ws;            // 512*128
    float* R = L + NI * DIM;            // 512*128

    ln_mean_project_kernel<<<NI, 512, 0, stream>>>(
        x, ln_g, ln_b, w_left, b_left, w_right, b_right, w_out, b_out, L, R);

    expand_kernel<<<2048, 256, 0, stream>>>((const f32x4*)L,
                                            (const f32x4*)R,
                                            (f32x4*)d_out);
}